// Round 2
// baseline (1959.824 us; speedup 1.0000x reference)
//
#include <hip/hip_runtime.h>
#include <math.h>

typedef short short8 __attribute__((ext_vector_type(8)));
typedef float floatx4 __attribute__((ext_vector_type(4)));

__device__ __forceinline__ unsigned short f2bf(float f) {
  unsigned int u = __builtin_bit_cast(unsigned int, f);
  u = (u + 0x7FFFu + ((u >> 16) & 1u)) >> 16;
  return (unsigned short)u;
}

__device__ __forceinline__ unsigned int pack_bf2(float lo, float hi) {
  return (unsigned int)f2bf(lo) | ((unsigned int)f2bf(hi) << 16);
}

__device__ __forceinline__ void async16(const void* g, void* l) {
  __builtin_amdgcn_global_load_lds(
      (const __attribute__((address_space(1))) unsigned int*)g,
      (__attribute__((address_space(3))) unsigned int*)l, 16, 0, 0);
}

// ---------------------------------------------------------------------------
// GEMM: out[M,N] = A[M,K] * B[N,K]^T + bias[N]   (A,B bf16 K-major)
// EPI: 0 = bf16 out, 1 = fp32 out, 2 = bf16 out + exact GELU,
//      3 = bf16 out, cols n<1024 scaled by 0.125 (Q pre-scale for attention)
// TM: 128 (2x2 waves, 4x4 acc) or 64 (1x4 waves, 4x2 acc; for N-starved GEMMs)
//
// R7/R8 pipeline restructure (R6 was staging-latency-bound: 1460 cyc/K-iter vs
// ~300 cyc of work; MfmaUtil 16%, HBM 25%, occupancy grid-capped at 2 blk/CU):
//  - 3-slot LDS ring, 2-deep global_load_lds prefetch, counted s_waitcnt
//    vmcnt(2*NL) in steady state (never drains to 0 mid-loop) + raw s_barrier.
//    Tile-t load latency hides under two full iterations of ds_read+MFMA.
//  - XOR chunk swizzle: global source chunk (tid&3)^((ar>>1)&3), LDS dest
//    stays linear (global_load_lds requirement); fragment read at
//    quad^((l15>>1)&3). Each consecutive-8-lane group hits all 8 16B LDS
//    slots -> 2-way (free) instead of 4-way bank conflict.
//  - lgkmcnt(0)+sched_barrier(0) BEFORE the second barrier: reads must be in
//    registers before any wave can re-stage this buffer (correctness).
//  - sched_barrier(0) AFTER the first barrier: pin ds_reads below s_barrier
//    (machine scheduler may otherwise hoist them above the raw barrier).
//  - s_setprio(1) around the MFMA cluster (T5; counted-vmcnt creates the
//    wave role-split it needs).
// ---------------------------------------------------------------------------
template <int EPI, int TM>
__global__ __launch_bounds__(256, 2) void gemm_bt(
    const unsigned short* __restrict__ A, const unsigned short* __restrict__ B,
    const float* __restrict__ bias, void* __restrict__ outp,
    int M, int N, int K) {
  constexpr int ABUF = TM * 32;                 // elems per A slot
  constexpr int NL = (TM == 128) ? 4 : 3;       // global_load_lds per thread/tile
  __shared__ unsigned short As[3 * ABUF];       // 3-slot ring
  __shared__ unsigned short Bs[3 * 4096];
  const int tid = threadIdx.x;
  const int lane = tid & 63;
  const int wid = tid >> 6;
  const int quad = lane >> 4, l15 = lane & 15;
  const int NI = 4, NJ = (TM == 128) ? 4 : 2;
  const int wm = (TM == 128) ? (wid >> 1) : 0;     // M wave offset (x64)
  const int wn = (TM == 128) ? (wid & 1) : wid;    // N wave offset (x64 / x32)
  const int nwoff = (TM == 128) ? wn * 64 : wn * 32;
  const size_t m0 = (size_t)blockIdx.y * TM, n0 = (size_t)blockIdx.x * 128;
  const int ar = tid >> 2;
  // pre-swizzled global source chunk: LDS slot (ar, tid&3) holds logical
  // k-chunk (tid&3) ^ ((ar>>1)&3)
  const int ak = (((tid & 3) ^ ((ar >> 1) & 3)) * 8);

  floatx4 acc[4][4] = {};

  auto stage = [&](int ib, int kk) {
    if (TM == 128) {
#pragma unroll
      for (int r = 0; r < 2; ++r) {
        int row = r * 64 + ar;
        async16(A + (m0 + row) * (size_t)K + kk + ak,
                &As[ib * ABUF + (r * 256 + tid) * 8]);
        async16(B + (n0 + row) * (size_t)K + kk + ak,
                &Bs[ib * 4096 + (r * 256 + tid) * 8]);
      }
    } else {
      async16(A + (m0 + ar) * (size_t)K + kk + ak, &As[ib * ABUF + tid * 8]);
#pragma unroll
      for (int r = 0; r < 2; ++r) {
        int row = r * 64 + ar;
        async16(B + (n0 + row) * (size_t)K + kk + ak,
                &Bs[ib * 4096 + (r * 256 + tid) * 8]);
      }
    }
  };

  stage(0, 0);
  if (K > 32) stage(1, 32);
  const int csw = (l15 >> 1) & 3;  // read-side chunk swizzle (row-derived)
  int ib = 0;

  for (int k0 = 0; k0 < K; k0 += 32) {
    int ib2 = ib + 2;
    if (ib2 >= 3) ib2 -= 3;
    if (k0 + 64 < K) {
      stage(ib2, k0 + 64);
      asm volatile("s_waitcnt vmcnt(%0)" ::"n"(2 * NL) : "memory");
    } else if (k0 + 32 < K) {
      asm volatile("s_waitcnt vmcnt(%0)" ::"n"(NL) : "memory");
    } else {
      asm volatile("s_waitcnt vmcnt(0)" ::: "memory");
    }
    __builtin_amdgcn_s_barrier();        // (1) buf[ib] fully staged, all waves
    __builtin_amdgcn_sched_barrier(0);   // pin ds_reads below the barrier

    short8 a[4], b[4];
#pragma unroll
    for (int i = 0; i < NI; ++i)
      a[i] = *(const short8*)&As[ib * ABUF + (wm * 64 + i * 16 + l15) * 32 +
                                 (quad ^ csw) * 8];
#pragma unroll
    for (int j = 0; j < NJ; ++j)
      b[j] = *(const short8*)&Bs[ib * 4096 + (nwoff + j * 16 + l15) * 32 +
                                 (quad ^ csw) * 8];
    asm volatile("s_waitcnt lgkmcnt(0)" ::: "memory");  // frags in regs
    __builtin_amdgcn_sched_barrier(0);                   // rule #18
    __builtin_amdgcn_s_barrier();        // (2) all waves done reading buf[ib]

    __builtin_amdgcn_s_setprio(1);
#pragma unroll
    for (int i = 0; i < NI; ++i)
#pragma unroll
      for (int j = 0; j < NJ; ++j)
        acc[i][j] = __builtin_amdgcn_mfma_f32_16x16x32_bf16(a[i], b[j],
                                                            acc[i][j], 0, 0, 0);
    __builtin_amdgcn_s_setprio(0);

    ib = ib + 1;
    if (ib >= 3) ib -= 3;
  }

#pragma unroll
  for (int j = 0; j < NJ; ++j) {
    const int n = (int)n0 + nwoff + j * 16 + l15;
    const float bv = bias[n];
    const float sc = (EPI == 3 && n < 1024) ? 0.125f : 1.0f;
#pragma unroll
    for (int i = 0; i < NI; ++i) {
      const int mbase = (int)m0 + wm * 64 + i * 16 + quad * 4;
#pragma unroll
      for (int r = 0; r < 4; ++r) {
        float v = acc[i][j][r] + bv;
        if (EPI == 2) v = 0.5f * v * (1.0f + erff(v * 0.70710678f));
        if (EPI == 3) v *= sc;
        size_t idx = (size_t)(mbase + r) * (size_t)N + n;
        if (EPI == 1) ((float*)outp)[idx] = v;
        else ((unsigned short*)outp)[idx] = f2bf(v);
      }
    }
  }
}

// ---------------------------------------------------------------------------
// Flash attention, sliding window (0 <= qpos-kpos <= 1000), 1 virtual past key
// (k=bk, v=bv). qkv: [B*T,3072] bf16 (0.125*q | k | v). Block = (qtile=128,
// head, batch), 8 waves x 16 queries.
// R6 restructure (R5 was VALU-bound: VALUBusy 39% vs MfmaUtil 5.7%):
//  - S^T = K*Q^T (swapped MFMA operands): lane holds 16 keys of ONE query
//    -> softmax reductions are per-lane, zero shuffles in the loop.
//  - No online max (scores tiny & shift-invariant; fp32 exp safe): e=exp(s).
//  - Wave-uniform skip of out-of-window tiles; mask-free interior fast path.
//  - Packed bf16 pair stores for P (adjacent keys per lane).
// ---------------------------------------------------------------------------
__global__ __launch_bounds__(512) void attn_kernel(
    const unsigned short* __restrict__ qkv, const float* __restrict__ bqkv_l,
    unsigned short* __restrict__ attno) {
  __shared__ unsigned short Qs[128 * 64];     // [q][d]
  __shared__ unsigned short Ks[64 * 64];      // [k][d]
  __shared__ unsigned short Vt[64 * 72];      // [d][k]  stride 72
  __shared__ unsigned short Ps[8][16 * 72];   // per-wave P [q][k] stride 72
  __shared__ float Lsh[8][16];                // per-wave softmax denominators

  const int qt = blockIdx.x, h = blockIdx.y, b = blockIdx.z;
  const int qs = qt * 128;
  const int tid = threadIdx.x, lane = tid & 63, wid = tid >> 6;
  const int quad = lane >> 4, l15 = lane & 15;
  const size_t rowbase = (size_t)b * 2048;
  const int hoff = h * 64;

#pragma unroll
  for (int r = 0; r < 2; ++r) {  // stage Q tile (16 KB)
    int c = r * 512 + tid;
    int qrow = c >> 3, ccq = c & 7;
    async16(qkv + (rowbase + qs + qrow) * 3072 + hoff + ccq * 8, &Qs[c * 8]);
  }

  floatx4 oacc[4] = {};
  float lpart = 0.f;  // this lane's partial denominator for q = l15

  int kstart = qs - 999;
  if (kstart < 0) kstart = 0;
  kstart &= ~63;
  const int kend = qs + 128;

  const int krow = tid >> 3, cc = tid & 7;   // staging coords (512 thr = 64x8)
  const int qlo = qs + wid * 16 + 1;         // min qpos in this wave
  const int qhi = qlo + 15;                  // max qpos in this wave
  const int qpos = qs + wid * 16 + l15 + 1;  // this lane's qpos (S^T: q = l15)

  for (int k0 = kstart; k0 <= kend; k0 += 64) {
    __syncthreads();
    {  // stage K tile (async, contiguous)
      int xr = k0 + krow - 1;
      xr = xr < 0 ? 0 : (xr > 2047 ? 2047 : xr);  // OOB rows masked later
      async16(qkv + (rowbase + xr) * 3072 + 1024 + hoff + cc * 8, &Ks[tid * 8]);
    }
    {  // stage V transposed; rotate element order by cc -> all 32 banks hit
      int xr = k0 + krow - 1;
      xr = xr < 0 ? 0 : (xr > 2047 ? 2047 : xr);
      short8 vv = *(const short8*)(qkv + (rowbase + xr) * 3072 + 2048 + hoff + cc * 8);
#pragma unroll
      for (int e = 0; e < 8; ++e) {
        int e2 = (e + cc) & 7;
        Vt[(cc * 8 + e2) * 72 + krow] = (unsigned short)vv[e2];
      }
    }
    if (k0 == 0) {  // virtual past key 0: k=bk, v=bv
      __syncthreads();
      if (tid < 64) {
        Ks[tid] = f2bf(bqkv_l[1024 + hoff + tid]);
        Vt[tid * 72] = f2bf(bqkv_l[2048 + hoff + tid]);
      }
    }
    __syncthreads();

    // wave-uniform: does this tile intersect this wave's window at all?
    if (k0 <= qhi && qlo - (k0 + 63) <= 1000) {
      // S^T = K*Q^T : D[key][q], key = nj*16+quad*4+r, q = l15
      floatx4 sacc[4] = {};
#pragma unroll
      for (int ks = 0; ks < 2; ++ks) {
        short8 bq = *(const short8*)&Qs[(wid * 16 + l15) * 64 + ks * 32 + quad * 8];
#pragma unroll
        for (int nj = 0; nj < 4; ++nj) {
          short8 ak = *(const short8*)&Ks[(nj * 16 + l15) * 64 + ks * 32 + quad * 8];
          sacc[nj] = __builtin_amdgcn_mfma_f32_16x16x32_bf16(ak, bq, sacc[nj], 0, 0, 0);
        }
      }

      const bool full = (k0 + 63 <= qlo) && (qhi - k0 <= 1000);
#pragma unroll
      for (int nj = 0; nj < 4; ++nj) {
        float e[4];
        if (full) {
#pragma unroll
          for (int r = 0; r < 4; ++r) e[r] = __expf(sacc[nj][r]);
        } else {
          const int keyb = k0 + nj * 16 + quad * 4;
#pragma unroll
          for (int r = 0; r < 4; ++r) {
            int delta = qpos - (keyb + r);
            e[r] = (delta >= 0 && delta <= 1000) ? __expf(sacc[nj][r]) : 0.f;
          }
        }
        lpart += (e[0] + e[1]) + (e[2] + e[3]);
        uint2 pk = make_uint2(pack_bf2(e[0], e[1]), pack_bf2(e[2], e[3]));
        *(uint2*)&Ps[wid][l15 * 72 + nj * 16 + quad * 4] = pk;
      }

      // O += P V  (Ps is wave-private; same-wave LDS ops are in-order)
#pragma unroll
      for (int ks = 0; ks < 2; ++ks) {
        short8 pf = *(const short8*)&Ps[wid][l15 * 72 + ks * 32 + quad * 8];
#pragma unroll
        for (int di = 0; di < 4; ++di) {
          short8 vf = *(const short8*)&Vt[(di * 16 + l15) * 72 + ks * 32 + quad * 8];
          oacc[di] = __builtin_amdgcn_mfma_f32_16x16x32_bf16(pf, vf, oacc[di], 0, 0, 0);
        }
      }
    }
  }

  // denominator: lpart is per (q=l15, quad) -> reduce over quads, redistribute
  lpart += __shfl_xor(lpart, 16);
  lpart += __shfl_xor(lpart, 32);
  if (quad == 0) Lsh[wid][l15] = lpart;
  __builtin_amdgcn_s_waitcnt(0);  // ds_write visible to own wave's reads
  float linv[4];
#pragma unroll
  for (int r = 0; r < 4; ++r) linv[r] = 1.0f / Lsh[wid][quad * 4 + r];

#pragma unroll
  for (int di = 0; di < 4; ++di)
#pragma unroll
    for (int r = 0; r < 4; ++r) {
      int q = qs + wid * 16 + quad * 4 + r;
      attno[(rowbase + q) * 1024 + hoff + di * 16 + l15] =
          f2bf(oacc[di][r] * linv[r]);
    }
}

// ---------------------------------------------------------------------------
// LN (+posemb) kernels: one block per row of 1024
// ---------------------------------------------------------------------------
__global__ __launch_bounds__(256) void ln_first_kernel(
    const float* __restrict__ xin, const float* __restrict__ g,
    const float* __restrict__ bb, float* __restrict__ xout,
    unsigned short* __restrict__ xbout) {
  const int row = blockIdx.x, tid = threadIdx.x;
  const size_t base = (size_t)row * 1024 + tid * 4;
  float4 xv = *(const float4*)&xin[base];
  float s = xv.x + xv.y + xv.z + xv.w;
  float sq = xv.x * xv.x + xv.y * xv.y + xv.z * xv.z + xv.w * xv.w;
  __shared__ float red[8];
  for (int off = 32; off > 0; off >>= 1) { s += __shfl_down(s, off); sq += __shfl_down(sq, off); }
  if ((tid & 63) == 0) { red[tid >> 6] = s; red[4 + (tid >> 6)] = sq; }
  __syncthreads();
  s = red[0] + red[1] + red[2] + red[3];
  sq = red[4] + red[5] + red[6] + red[7];
  const float mean = s * (1.f / 1024.f);
  const float rstd = rsqrtf(sq * (1.f / 1024.f) - mean * mean + 1e-5f);
  float4 gv = *(const float4*)&g[tid * 4];
  float4 bv = *(const float4*)&bb[tid * 4];
  const float tf = (float)(row & 2047);
  float xs[4] = {xv.x, xv.y, xv.z, xv.w};
  float gs[4] = {gv.x, gv.y, gv.z, gv.w};
  float bs[4] = {bv.x, bv.y, bv.z, bv.w};
  float y[4];
#pragma unroll
  for (int e = 0; e < 4; ++e) {
    int c = tid * 4 + e;
    float a = (c < 512) ? (float)c : (float)(c - 512);
    float ph = tf * powf(10000.f, -a * (1.f / 511.f));
    float pe = (c < 512) ? cosf(ph) : sinf(ph);
    y[e] = (xs[e] - mean) * rstd * gs[e] + bs[e] + pe;
  }
  *(float4*)&xout[base] = make_float4(y[0], y[1], y[2], y[3]);
  *(ushort4*)&xbout[base] = make_ushort4(f2bf(y[0]), f2bf(y[1]), f2bf(y[2]), f2bf(y[3]));
}

__global__ __launch_bounds__(256) void ln_res_kernel(
    const float* __restrict__ xin, const float* __restrict__ addv,
    const float* __restrict__ g, const float* __restrict__ bb,
    float* __restrict__ xout, unsigned short* __restrict__ xbout) {
  const int row = blockIdx.x, tid = threadIdx.x;
  const size_t base = (size_t)row * 1024 + tid * 4;
  float4 xv = *(const float4*)&xin[base];
  float4 av = *(const float4*)&addv[base];
  float v0 = xv.x + av.x, v1 = xv.y + av.y, v2 = xv.z + av.z, v3 = xv.w + av.w;
  float s = v0 + v1 + v2 + v3;
  float sq = v0 * v0 + v1 * v1 + v2 * v2 + v3 * v3;
  __shared__ float red[8];
  for (int off = 32; off > 0; off >>= 1) { s += __shfl_down(s, off); sq += __shfl_down(sq, off); }
  if ((tid & 63) == 0) { red[tid >> 6] = s; red[4 + (tid >> 6)] = sq; }
  __syncthreads();
  s = red[0] + red[1] + red[2] + red[3];
  sq = red[4] + red[5] + red[6] + red[7];
  const float mean = s * (1.f / 1024.f);
  const float rstd = rsqrtf(sq * (1.f / 1024.f) - mean * mean + 1e-5f);
  float4 gv = *(const float4*)&g[tid * 4];
  float4 bv = *(const float4*)&bb[tid * 4];
  float vs[4] = {v0, v1, v2, v3};
  float gs[4] = {gv.x, gv.y, gv.z, gv.w};
  float bs[4] = {bv.x, bv.y, bv.z, bv.w};
  float y[4];
#pragma unroll
  for (int e = 0; e < 4; ++e) y[e] = (vs[e] - mean) * rstd * gs[e] + bs[e];
  *(float4*)&xout[base] = make_float4(y[0], y[1], y[2], y[3]);
  if (xbout)
    *(ushort4*)&xbout[base] = make_ushort4(f2bf(y[0]), f2bf(y[1]), f2bf(y[2]), f2bf(y[3]));
}

// fp32 -> bf16 weight conversion for one layer (Wqkv|Wo|W1|W2 concat)
__global__ __launch_bounds__(256) void convw_kernel(
    const float* __restrict__ wqkv, const float* __restrict__ wo,
    const float* __restrict__ w1, const float* __restrict__ w2,
    unsigned short* __restrict__ dst) {
  for (int base = blockIdx.x * 256 + threadIdx.x; base < 3145728; base += 786432) {
    int i = base << 2;
    const float* src;
    int off;
    if (i < 3145728)      { src = wqkv; off = i; }
    else if (i < 4194304) { src = wo;   off = i - 3145728; }
    else if (i < 8388608) { src = w1;   off = i - 4194304; }
    else                  { src = w2;   off = i - 8388608; }
    float4 v = *(const float4*)&src[off];
    *(ushort4*)&dst[i] = make_ushort4(f2bf(v.x), f2bf(v.y), f2bf(v.z), f2bf(v.w));
  }
}

// ---------------------------------------------------------------------------
extern "C" void kernel_launch(void* const* d_in, const int* in_sizes, int n_in,
                              void* d_out, int out_size, void* d_ws, size_t ws_size,
                              hipStream_t stream) {
  const float* x    = (const float*)d_in[0];
  const float* ng   = (const float*)d_in[1];
  const float* nb   = (const float*)d_in[2];
  const float* Wqkv = (const float*)d_in[3];
  const float* bqkv = (const float*)d_in[4];
  const float* Wo   = (const float*)d_in[5];
  const float* bo   = (const float*)d_in[6];
  const float* ln1g = (const float*)d_in[7];
  const float* ln1b = (const float*)d_in[8];
  const float* ln2g = (const float*)d_in[9];
  const float* ln2b = (const float*)d_in[10];
  const float* W1   = (const float*)d_in[11];
  const float* b1   = (const float*)d_in[12];
  const float* W2   = (const float*)d_in[13];
  const float* b2   = (const float*)d_in[14];

  char* ws = (char*)d_ws;  // total footprint: exactly 128 MiB
  float* xf           = (float*)(ws + 0);          // 16 MB fp32 residual stream
  unsigned short* xb  = (unsigned short*)(ws + 16777216);   // 8 MB bf16 copy
  unsigned short* qkv = (unsigned short*)(ws + 25165824);   // 24 MB bf16 [4096,3072]
  unsigned short* att = (unsigned short*)(ws + 50331648);   // 8 MB bf16
  unsigned short* h1  = (unsigned short*)(ws + 58720256);   // 32 MB bf16 [4096,4096]
  float* gout         = (float*)(ws + 92274688);            // 16 MB fp32 GEMM out
  unsigned short* wb  = (unsigned short*)(ws + 109051904);  // 24 MB bf16 weights
  unsigned short* wqkvb = wb;
  unsigned short* wob   = wb + 3145728;
  unsigned short* w1b   = wb + 4194304;
  unsigned short* w2b   = wb + 8388608;

  ln_first_kernel<<<4096, 256, 0, stream>>>(x, ng, nb, xf, xb);

  for (int l = 0; l < 6; ++l) {
    convw_kernel<<<3072, 256, 0, stream>>>(Wqkv + (size_t)l * 3145728,
                                           Wo + (size_t)l * 1048576,
                                           W1 + (size_t)l * 4194304,
                                           W2 + (size_t)l * 4194304, wb);
    gemm_bt<3, 128><<<dim3(24, 32), 256, 0, stream>>>(xb, wqkvb, bqkv + l * 3072, qkv,
                                                      4096, 3072, 1024);
    attn_kernel<<<dim3(16, 16, 2), 512, 0, stream>>>(qkv, bqkv + l * 3072, att);
    gemm_bt<1, 64><<<dim3(8, 64), 256, 0, stream>>>(att, wob, bo + l * 1024, gout,
                                                    4096, 1024, 1024);
    ln_res_kernel<<<4096, 256, 0, stream>>>(xf, gout, ln1g + l * 1024, ln1b + l * 1024,
                                            xf, xb);
    gemm_bt<2, 128><<<dim3(32, 32), 256, 0, stream>>>(xb, w1b, b1 + l * 4096, h1,
                                                      4096, 4096, 1024);
    gemm_bt<1, 64><<<dim3(8, 64), 256, 0, stream>>>(h1, w2b, b2 + l * 1024, gout,
                                                    4096, 1024, 4096);
    // Final output is fp32: last LN writes directly to d_out as float.
    ln_res_kernel<<<4096, 256, 0, stream>>>(xf, gout, ln2g + l * 1024, ln2b + l * 1024,
                                            (l == 5) ? (float*)d_out : xf,
                                            (l == 5) ? nullptr : xb);
  }
}

// Round 3
// 1752.097 us; speedup vs baseline: 1.1186x; 1.1186x over previous
//
#include <hip/hip_runtime.h>
#include <math.h>

typedef short short8 __attribute__((ext_vector_type(8)));
typedef float floatx4 __attribute__((ext_vector_type(4)));

__device__ __forceinline__ unsigned short f2bf(float f) {
  unsigned int u = __builtin_bit_cast(unsigned int, f);
  u = (u + 0x7FFFu + ((u >> 16) & 1u)) >> 16;
  return (unsigned short)u;
}

__device__ __forceinline__ unsigned int pack_bf2(float lo, float hi) {
  return (unsigned int)f2bf(lo) | ((unsigned int)f2bf(hi) << 16);
}

__device__ __forceinline__ void async16(const void* g, void* l) {
  __builtin_amdgcn_global_load_lds(
      (const __attribute__((address_space(1))) unsigned int*)g,
      (__attribute__((address_space(3))) unsigned int*)l, 16, 0, 0);
}

// ---------------------------------------------------------------------------
// GEMM R3: out[M,N] = A[M,K] * B[N,K]^T + bias[N]   (A,B bf16 K-major)
// EPI: 1 = fp32 out, 2 = bf16 + exact GELU, 3 = bf16, n<1024 scaled 0.125
// BM: 256 (waves 4Mx2N, per-wave 64x64) or 128 (waves 2Mx4N, per-wave 64x32)
// BN fixed 128. BK=64. 512 threads.
//
// Structure (R2 post-mortem: 2-phase loop null per regime-gate; 421 TF,
// cache-BW bound at 128^2 tile):
//  - TRIPLE-buffered LDS ring at K-tile granularity; tile t+2 staged at
//    iter t; steady-state s_waitcnt vmcnt(2*NLT) retires exactly the
//    2-iter-old group -> every global_load_lds gets ~2 tiles of compute
//    (>= 1500 cyc) to land. Never drains mid-loop (T3/T4).
//  - 2 raw barriers/iter: (1) post-vmcnt = buf[cur] staged collectively;
//    (2) post-lgkmcnt(0) = all waves' frags in regs, so next iter's stage
//    of buf[cur] (= (t+3)%3) cannot race any wave's reads.
//  - XOR chunk swizzle for 128B LDS rows (G4 fix): logical chunk c lives at
//    physical chunk c^(row&7). Source pre-swizzled, LDS dest stays linear
//    (dest elem = 8*ci identity), reads apply the same XOR.
//  - XCD-aware bijective block swizzle (all grids %8==0): each XCD gets a
//    contiguous tile range -> A-panels L2-resident per XCD.
//  - s_setprio(1) around MFMA cluster (T5).
// ---------------------------------------------------------------------------
template <int EPI, int BM>
__global__ __launch_bounds__(512, 2) void gemm3(
    const unsigned short* __restrict__ A, const unsigned short* __restrict__ B,
    const float* __restrict__ bias, void* __restrict__ outp,
    int M, int N, int K) {
  constexpr int BN = 128;
  constexpr int ROWS = BM + BN;           // A rows then B rows per buffer
  constexpr int BUFE = ROWS * 64;         // elems per buffer
  constexpr int NLT = ROWS / 64;          // gloads/thread/tile (6 or 4)
  constexpr int WM = BM / 64;             // waves along M (4 or 2)
  constexpr int WN = 8 / WM;              // waves along N (2 or 4)
  constexpr int NJ = (BN / WN) / 16;      // 2 or 4 j-fragments
  __shared__ unsigned short S[3 * BUFE];  // 144 KB (BM=256) / 96 KB (BM=128)

  const int tid = threadIdx.x;
  const int lane = tid & 63, wid = tid >> 6;
  const int quad = lane >> 4, l15 = lane & 15;
  const int wm = wid / WN, wn = wid % WN;
  const int wmo = wm * 64;
  const int wno = wn * (BN / WN);

  // XCD-aware bijective swizzle (nwg % 8 == 0 for all launches)
  const int gx = gridDim.x;
  const int nwg = gx * gridDim.y;
  int lin = blockIdx.y * gx + blockIdx.x;
  lin = (lin & 7) * (nwg >> 3) + (lin >> 3);
  const size_t m0 = (size_t)(lin / gx) * BM;
  const size_t n0 = (size_t)(lin % gx) * BN;

  auto stage = [&](int buf, int kt) {
#pragma unroll
    for (int l = 0; l < NLT; ++l) {
      int ci = l * 512 + tid;
      int r = ci >> 3;
      int c = (ci & 7) ^ (r & 7);  // pre-swizzled logical chunk
      const unsigned short* src =
          (r < BM) ? A + (m0 + r) * (size_t)K + kt + c * 8
                   : B + (n0 + (r - BM)) * (size_t)K + kt + c * 8;
      async16(src, &S[buf * BUFE + ci * 8]);  // dest = 8*ci: lane-linear
    }
  };

  floatx4 acc[4][NJ] = {};

  stage(0, 0);
  stage(1, 64);
  int cur = 0;

  for (int kt = 0; kt < K; kt += 64) {
    if (kt + 128 < K) {
      int nb = cur + 2;
      if (nb >= 3) nb -= 3;
      stage(nb, kt + 128);
      asm volatile("s_waitcnt vmcnt(%0)" ::"n"(2 * NLT) : "memory");
    } else if (kt + 64 < K) {
      asm volatile("s_waitcnt vmcnt(%0)" ::"n"(NLT) : "memory");
    } else {
      asm volatile("s_waitcnt vmcnt(0)" ::: "memory");
    }
    __builtin_amdgcn_s_barrier();       // (1) buf[cur] staged, all waves
    __builtin_amdgcn_sched_barrier(0);  // pin reads below the barrier

    short8 a[4][2], b[NJ][2];
    const unsigned short* Sc = &S[cur * BUFE];
#pragma unroll
    for (int i = 0; i < 4; ++i) {
      const int R = wmo + i * 16 + l15;
#pragma unroll
      for (int kh = 0; kh < 2; ++kh)
        a[i][kh] = *(const short8*)&Sc[R * 64 + (((kh * 4 + quad) ^ (R & 7)) * 8)];
    }
#pragma unroll
    for (int j = 0; j < NJ; ++j) {
      const int R = BM + wno + j * 16 + l15;
#pragma unroll
      for (int kh = 0; kh < 2; ++kh)
        b[j][kh] = *(const short8*)&Sc[R * 64 + (((kh * 4 + quad) ^ (R & 7)) * 8)];
    }
    asm volatile("s_waitcnt lgkmcnt(0)" ::: "memory");  // frags in regs
    __builtin_amdgcn_sched_barrier(0);
    __builtin_amdgcn_s_barrier();       // (2) all reads done -> buf reusable

    __builtin_amdgcn_s_setprio(1);
#pragma unroll
    for (int kh = 0; kh < 2; ++kh)
#pragma unroll
      for (int i = 0; i < 4; ++i)
#pragma unroll
        for (int j = 0; j < NJ; ++j)
          acc[i][j] = __builtin_amdgcn_mfma_f32_16x16x32_bf16(
              a[i][kh], b[j][kh], acc[i][j], 0, 0, 0);
    __builtin_amdgcn_s_setprio(0);

    ++cur;
    if (cur >= 3) cur -= 3;
  }

#pragma unroll
  for (int j = 0; j < NJ; ++j) {
    const int n = (int)n0 + wno + j * 16 + l15;
    const float bv = bias[n];
    const float sc = (EPI == 3 && n < 1024) ? 0.125f : 1.0f;
#pragma unroll
    for (int i = 0; i < 4; ++i) {
      const int mbase = (int)m0 + wmo + i * 16 + quad * 4;
#pragma unroll
      for (int r = 0; r < 4; ++r) {
        float v = acc[i][j][r] + bv;
        if (EPI == 2) v = 0.5f * v * (1.0f + erff(v * 0.70710678f));
        if (EPI == 3) v *= sc;
        size_t idx = (size_t)(mbase + r) * (size_t)N + n;
        if (EPI == 1) ((float*)outp)[idx] = v;
        else ((unsigned short*)outp)[idx] = f2bf(v);
      }
    }
  }
}

// ---------------------------------------------------------------------------
// Flash attention, sliding window (0 <= qpos-kpos <= 1000), 1 virtual past key
// (k=bk, v=bv). qkv: [B*T,3072] bf16 (0.125*q | k | v). Block = (qtile=128,
// head, batch), 8 waves x 16 queries.  (unchanged from R2)
// ---------------------------------------------------------------------------
__global__ __launch_bounds__(512) void attn_kernel(
    const unsigned short* __restrict__ qkv, const float* __restrict__ bqkv_l,
    unsigned short* __restrict__ attno) {
  __shared__ unsigned short Qs[128 * 64];     // [q][d]
  __shared__ unsigned short Ks[64 * 64];      // [k][d]
  __shared__ unsigned short Vt[64 * 72];      // [d][k]  stride 72
  __shared__ unsigned short Ps[8][16 * 72];   // per-wave P [q][k] stride 72
  __shared__ float Lsh[8][16];                // per-wave softmax denominators

  const int qt = blockIdx.x, h = blockIdx.y, b = blockIdx.z;
  const int qs = qt * 128;
  const int tid = threadIdx.x, lane = tid & 63, wid = tid >> 6;
  const int quad = lane >> 4, l15 = lane & 15;
  const size_t rowbase = (size_t)b * 2048;
  const int hoff = h * 64;

#pragma unroll
  for (int r = 0; r < 2; ++r) {  // stage Q tile (16 KB)
    int c = r * 512 + tid;
    int qrow = c >> 3, ccq = c & 7;
    async16(qkv + (rowbase + qs + qrow) * 3072 + hoff + ccq * 8, &Qs[c * 8]);
  }

  floatx4 oacc[4] = {};
  float lpart = 0.f;  // this lane's partial denominator for q = l15

  int kstart = qs - 999;
  if (kstart < 0) kstart = 0;
  kstart &= ~63;
  const int kend = qs + 128;

  const int krow = tid >> 3, cc = tid & 7;   // staging coords (512 thr = 64x8)
  const int qlo = qs + wid * 16 + 1;         // min qpos in this wave
  const int qhi = qlo + 15;                  // max qpos in this wave
  const int qpos = qs + wid * 16 + l15 + 1;  // this lane's qpos (S^T: q = l15)

  for (int k0 = kstart; k0 <= kend; k0 += 64) {
    __syncthreads();
    {  // stage K tile (async, contiguous)
      int xr = k0 + krow - 1;
      xr = xr < 0 ? 0 : (xr > 2047 ? 2047 : xr);  // OOB rows masked later
      async16(qkv + (rowbase + xr) * 3072 + 1024 + hoff + cc * 8, &Ks[tid * 8]);
    }
    {  // stage V transposed; rotate element order by cc -> all 32 banks hit
      int xr = k0 + krow - 1;
      xr = xr < 0 ? 0 : (xr > 2047 ? 2047 : xr);
      short8 vv = *(const short8*)(qkv + (rowbase + xr) * 3072 + 2048 + hoff + cc * 8);
#pragma unroll
      for (int e = 0; e < 8; ++e) {
        int e2 = (e + cc) & 7;
        Vt[(cc * 8 + e2) * 72 + krow] = (unsigned short)vv[e2];
      }
    }
    if (k0 == 0) {  // virtual past key 0: k=bk, v=bv
      __syncthreads();
      if (tid < 64) {
        Ks[tid] = f2bf(bqkv_l[1024 + hoff + tid]);
        Vt[tid * 72] = f2bf(bqkv_l[2048 + hoff + tid]);
      }
    }
    __syncthreads();

    // wave-uniform: does this tile intersect this wave's window at all?
    if (k0 <= qhi && qlo - (k0 + 63) <= 1000) {
      // S^T = K*Q^T : D[key][q], key = nj*16+quad*4+r, q = l15
      floatx4 sacc[4] = {};
#pragma unroll
      for (int ks = 0; ks < 2; ++ks) {
        short8 bq = *(const short8*)&Qs[(wid * 16 + l15) * 64 + ks * 32 + quad * 8];
#pragma unroll
        for (int nj = 0; nj < 4; ++nj) {
          short8 ak = *(const short8*)&Ks[(nj * 16 + l15) * 64 + ks * 32 + quad * 8];
          sacc[nj] = __builtin_amdgcn_mfma_f32_16x16x32_bf16(ak, bq, sacc[nj], 0, 0, 0);
        }
      }

      const bool full = (k0 + 63 <= qlo) && (qhi - k0 <= 1000);
#pragma unroll
      for (int nj = 0; nj < 4; ++nj) {
        float e[4];
        if (full) {
#pragma unroll
          for (int r = 0; r < 4; ++r) e[r] = __expf(sacc[nj][r]);
        } else {
          const int keyb = k0 + nj * 16 + quad * 4;
#pragma unroll
          for (int r = 0; r < 4; ++r) {
            int delta = qpos - (keyb + r);
            e[r] = (delta >= 0 && delta <= 1000) ? __expf(sacc[nj][r]) : 0.f;
          }
        }
        lpart += (e[0] + e[1]) + (e[2] + e[3]);
        uint2 pk = make_uint2(pack_bf2(e[0], e[1]), pack_bf2(e[2], e[3]));
        *(uint2*)&Ps[wid][l15 * 72 + nj * 16 + quad * 4] = pk;
      }

      // O += P V  (Ps is wave-private; same-wave LDS ops are in-order)
#pragma unroll
      for (int ks = 0; ks < 2; ++ks) {
        short8 pf = *(const short8*)&Ps[wid][l15 * 72 + ks * 32 + quad * 8];
#pragma unroll
        for (int di = 0; di < 4; ++di) {
          short8 vf = *(const short8*)&Vt[(di * 16 + l15) * 72 + ks * 32 + quad * 8];
          oacc[di] = __builtin_amdgcn_mfma_f32_16x16x32_bf16(pf, vf, oacc[di], 0, 0, 0);
        }
      }
    }
  }

  // denominator: lpart is per (q=l15, quad) -> reduce over quads, redistribute
  lpart += __shfl_xor(lpart, 16);
  lpart += __shfl_xor(lpart, 32);
  if (quad == 0) Lsh[wid][l15] = lpart;
  __builtin_amdgcn_s_waitcnt(0);  // ds_write visible to own wave's reads
  float linv[4];
#pragma unroll
  for (int r = 0; r < 4; ++r) linv[r] = 1.0f / Lsh[wid][quad * 4 + r];

#pragma unroll
  for (int di = 0; di < 4; ++di)
#pragma unroll
    for (int r = 0; r < 4; ++r) {
      int q = qs + wid * 16 + quad * 4 + r;
      attno[(rowbase + q) * 1024 + hoff + di * 16 + l15] =
          f2bf(oacc[di][r] * linv[r]);
    }
}

// ---------------------------------------------------------------------------
// LN (+posemb) kernels: one block per row of 1024  (unchanged)
// ---------------------------------------------------------------------------
__global__ __launch_bounds__(256) void ln_first_kernel(
    const float* __restrict__ xin, const float* __restrict__ g,
    const float* __restrict__ bb, float* __restrict__ xout,
    unsigned short* __restrict__ xbout) {
  const int row = blockIdx.x, tid = threadIdx.x;
  const size_t base = (size_t)row * 1024 + tid * 4;
  float4 xv = *(const float4*)&xin[base];
  float s = xv.x + xv.y + xv.z + xv.w;
  float sq = xv.x * xv.x + xv.y * xv.y + xv.z * xv.z + xv.w * xv.w;
  __shared__ float red[8];
  for (int off = 32; off > 0; off >>= 1) { s += __shfl_down(s, off); sq += __shfl_down(sq, off); }
  if ((tid & 63) == 0) { red[tid >> 6] = s; red[4 + (tid >> 6)] = sq; }
  __syncthreads();
  s = red[0] + red[1] + red[2] + red[3];
  sq = red[4] + red[5] + red[6] + red[7];
  const float mean = s * (1.f / 1024.f);
  const float rstd = rsqrtf(sq * (1.f / 1024.f) - mean * mean + 1e-5f);
  float4 gv = *(const float4*)&g[tid * 4];
  float4 bv = *(const float4*)&bb[tid * 4];
  const float tf = (float)(row & 2047);
  float xs[4] = {xv.x, xv.y, xv.z, xv.w};
  float gs[4] = {gv.x, gv.y, gv.z, gv.w};
  float bs[4] = {bv.x, bv.y, bv.z, bv.w};
  float y[4];
#pragma unroll
  for (int e = 0; e < 4; ++e) {
    int c = tid * 4 + e;
    float a = (c < 512) ? (float)c : (float)(c - 512);
    float ph = tf * powf(10000.f, -a * (1.f / 511.f));
    float pe = (c < 512) ? cosf(ph) : sinf(ph);
    y[e] = (xs[e] - mean) * rstd * gs[e] + bs[e] + pe;
  }
  *(float4*)&xout[base] = make_float4(y[0], y[1], y[2], y[3]);
  *(ushort4*)&xbout[base] = make_ushort4(f2bf(y[0]), f2bf(y[1]), f2bf(y[2]), f2bf(y[3]));
}

__global__ __launch_bounds__(256) void ln_res_kernel(
    const float* __restrict__ xin, const float* __restrict__ addv,
    const float* __restrict__ g, const float* __restrict__ bb,
    float* __restrict__ xout, unsigned short* __restrict__ xbout) {
  const int row = blockIdx.x, tid = threadIdx.x;
  const size_t base = (size_t)row * 1024 + tid * 4;
  float4 xv = *(const float4*)&xin[base];
  float4 av = *(const float4*)&addv[base];
  float v0 = xv.x + av.x, v1 = xv.y + av.y, v2 = xv.z + av.z, v3 = xv.w + av.w;
  float s = v0 + v1 + v2 + v3;
  float sq = v0 * v0 + v1 * v1 + v2 * v2 + v3 * v3;
  __shared__ float red[8];
  for (int off = 32; off > 0; off >>= 1) { s += __shfl_down(s, off); sq += __shfl_down(sq, off); }
  if ((tid & 63) == 0) { red[tid >> 6] = s; red[4 + (tid >> 6)] = sq; }
  __syncthreads();
  s = red[0] + red[1] + red[2] + red[3];
  sq = red[4] + red[5] + red[6] + red[7];
  const float mean = s * (1.f / 1024.f);
  const float rstd = rsqrtf(sq * (1.f / 1024.f) - mean * mean + 1e-5f);
  float4 gv = *(const float4*)&g[tid * 4];
  float4 bv = *(const float4*)&bb[tid * 4];
  float vs[4] = {v0, v1, v2, v3};
  float gs[4] = {gv.x, gv.y, gv.z, gv.w};
  float bs[4] = {bv.x, bv.y, bv.z, bv.w};
  float y[4];
#pragma unroll
  for (int e = 0; e < 4; ++e) y[e] = (vs[e] - mean) * rstd * gs[e] + bs[e];
  *(float4*)&xout[base] = make_float4(y[0], y[1], y[2], y[3]);
  if (xbout)
    *(ushort4*)&xbout[base] = make_ushort4(f2bf(y[0]), f2bf(y[1]), f2bf(y[2]), f2bf(y[3]));
}

// fp32 -> bf16 weight conversion for one layer (Wqkv|Wo|W1|W2 concat)
__global__ __launch_bounds__(256) void convw_kernel(
    const float* __restrict__ wqkv, const float* __restrict__ wo,
    const float* __restrict__ w1, const float* __restrict__ w2,
    unsigned short* __restrict__ dst) {
  for (int base = blockIdx.x * 256 + threadIdx.x; base < 3145728; base += 786432) {
    int i = base << 2;
    const float* src;
    int off;
    if (i < 3145728)      { src = wqkv; off = i; }
    else if (i < 4194304) { src = wo;   off = i - 3145728; }
    else if (i < 8388608) { src = w1;   off = i - 4194304; }
    else                  { src = w2;   off = i - 8388608; }
    float4 v = *(const float4*)&src[off];
    *(ushort4*)&dst[i] = make_ushort4(f2bf(v.x), f2bf(v.y), f2bf(v.z), f2bf(v.w));
  }
}

// ---------------------------------------------------------------------------
extern "C" void kernel_launch(void* const* d_in, const int* in_sizes, int n_in,
                              void* d_out, int out_size, void* d_ws, size_t ws_size,
                              hipStream_t stream) {
  const float* x    = (const float*)d_in[0];
  const float* ng   = (const float*)d_in[1];
  const float* nb   = (const float*)d_in[2];
  const float* Wqkv = (const float*)d_in[3];
  const float* bqkv = (const float*)d_in[4];
  const float* Wo   = (const float*)d_in[5];
  const float* bo   = (const float*)d_in[6];
  const float* ln1g = (const float*)d_in[7];
  const float* ln1b = (const float*)d_in[8];
  const float* ln2g = (const float*)d_in[9];
  const float* ln2b = (const float*)d_in[10];
  const float* W1   = (const float*)d_in[11];
  const float* b1   = (const float*)d_in[12];
  const float* W2   = (const float*)d_in[13];
  const float* b2   = (const float*)d_in[14];

  char* ws = (char*)d_ws;  // total footprint: exactly 128 MiB
  float* xf           = (float*)(ws + 0);          // 16 MB fp32 residual stream
  unsigned short* xb  = (unsigned short*)(ws + 16777216);   // 8 MB bf16 copy
  unsigned short* qkv = (unsigned short*)(ws + 25165824);   // 24 MB bf16 [4096,3072]
  unsigned short* att = (unsigned short*)(ws + 50331648);   // 8 MB bf16
  unsigned short* h1  = (unsigned short*)(ws + 58720256);   // 32 MB bf16 [4096,4096]
  float* gout         = (float*)(ws + 92274688);            // 16 MB fp32 GEMM out
  unsigned short* wb  = (unsigned short*)(ws + 109051904);  // 24 MB bf16 weights
  unsigned short* wqkvb = wb;
  unsigned short* wob   = wb + 3145728;
  unsigned short* w1b   = wb + 4194304;
  unsigned short* w2b   = wb + 8388608;

  ln_first_kernel<<<4096, 256, 0, stream>>>(x, ng, nb, xf, xb);

  for (int l = 0; l < 6; ++l) {
    convw_kernel<<<3072, 256, 0, stream>>>(Wqkv + (size_t)l * 3145728,
                                           Wo + (size_t)l * 1048576,
                                           W1 + (size_t)l * 4194304,
                                           W2 + (size_t)l * 4194304, wb);
    gemm3<3, 256><<<dim3(24, 16), 512, 0, stream>>>(xb, wqkvb, bqkv + l * 3072, qkv,
                                                    4096, 3072, 1024);
    attn_kernel<<<dim3(16, 16, 2), 512, 0, stream>>>(qkv, bqkv + l * 3072, att);
    gemm3<1, 128><<<dim3(8, 32), 512, 0, stream>>>(att, wob, bo + l * 1024, gout,
                                                   4096, 1024, 1024);
    ln_res_kernel<<<4096, 256, 0, stream>>>(xf, gout, ln1g + l * 1024, ln1b + l * 1024,
                                            xf, xb);
    gemm3<2, 256><<<dim3(32, 16), 512, 0, stream>>>(xb, w1b, b1 + l * 4096, h1,
                                                    4096, 4096, 1024);
    gemm3<1, 128><<<dim3(8, 32), 512, 0, stream>>>(h1, w2b, b2 + l * 1024, gout,
                                                   4096, 1024, 4096);
    // Final output is fp32: last LN writes directly to d_out as float.
    ln_res_kernel<<<4096, 256, 0, stream>>>(xf, gout, ln2g + l * 1024, ln2b + l * 1024,
                                            (l == 5) ? (float*)d_out : xf,
                                            (l == 5) ? nullptr : xb);
  }
}

// Round 5
// 1738.946 us; speedup vs baseline: 1.1270x; 1.0076x over previous
//
#include <hip/hip_runtime.h>
#include <math.h>

typedef short short8 __attribute__((ext_vector_type(8)));
typedef float floatx4 __attribute__((ext_vector_type(4)));

__device__ __forceinline__ unsigned short f2bf(float f) {
  unsigned int u = __builtin_bit_cast(unsigned int, f);
  u = (u + 0x7FFFu + ((u >> 16) & 1u)) >> 16;
  return (unsigned short)u;
}

__device__ __forceinline__ unsigned int pack_bf2(float lo, float hi) {
  return (unsigned int)f2bf(lo) | ((unsigned int)f2bf(hi) << 16);
}

__device__ __forceinline__ void async16(const void* g, void* l) {
  __builtin_amdgcn_global_load_lds(
      (const __attribute__((address_space(1))) unsigned int*)g,
      (__attribute__((address_space(3))) unsigned int*)l, 16, 0, 0);
}

// ---------------------------------------------------------------------------
// GEMM R3 (unchanged; verified): out[M,N] = A[M,K]*B[N,K]^T + bias[N]
// EPI: 1 = fp32 out, 2 = bf16 + exact GELU, 3 = bf16, n<1024 scaled 0.125
// BM: 256 (waves 4Mx2N) or 128 (waves 2Mx4N). BN=128. BK=64. 512 threads.
// Triple-buffered ring, counted vmcnt(2*NLT), XOR chunk swizzle, XCD swizzle.
// ---------------------------------------------------------------------------
template <int EPI, int BM>
__global__ __launch_bounds__(512, 2) void gemm3(
    const unsigned short* __restrict__ A, const unsigned short* __restrict__ B,
    const float* __restrict__ bias, void* __restrict__ outp,
    int M, int N, int K) {
  constexpr int BN = 128;
  constexpr int ROWS = BM + BN;           // A rows then B rows per buffer
  constexpr int BUFE = ROWS * 64;         // elems per buffer
  constexpr int NLT = ROWS / 64;          // gloads/thread/tile (6 or 4)
  constexpr int WM = BM / 64;             // waves along M (4 or 2)
  constexpr int WN = 8 / WM;              // waves along N (2 or 4)
  constexpr int NJ = (BN / WN) / 16;      // 2 or 4 j-fragments
  __shared__ unsigned short S[3 * BUFE];  // 144 KB (BM=256) / 96 KB (BM=128)

  const int tid = threadIdx.x;
  const int lane = tid & 63, wid = tid >> 6;
  const int quad = lane >> 4, l15 = lane & 15;
  const int wm = wid / WN, wn = wid % WN;
  const int wmo = wm * 64;
  const int wno = wn * (BN / WN);

  // XCD-aware bijective swizzle (nwg % 8 == 0 for all launches)
  const int gx = gridDim.x;
  const int nwg = gx * gridDim.y;
  int lin = blockIdx.y * gx + blockIdx.x;
  lin = (lin & 7) * (nwg >> 3) + (lin >> 3);
  const size_t m0 = (size_t)(lin / gx) * BM;
  const size_t n0 = (size_t)(lin % gx) * BN;

  auto stage = [&](int buf, int kt) {
#pragma unroll
    for (int l = 0; l < NLT; ++l) {
      int ci = l * 512 + tid;
      int r = ci >> 3;
      int c = (ci & 7) ^ (r & 7);  // pre-swizzled logical chunk
      const unsigned short* src =
          (r < BM) ? A + (m0 + r) * (size_t)K + kt + c * 8
                   : B + (n0 + (r - BM)) * (size_t)K + kt + c * 8;
      async16(src, &S[buf * BUFE + ci * 8]);  // dest = 8*ci: lane-linear
    }
  };

  floatx4 acc[4][NJ] = {};

  stage(0, 0);
  stage(1, 64);
  int cur = 0;

  for (int kt = 0; kt < K; kt += 64) {
    if (kt + 128 < K) {
      int nb = cur + 2;
      if (nb >= 3) nb -= 3;
      stage(nb, kt + 128);
      asm volatile("s_waitcnt vmcnt(%0)" ::"n"(2 * NLT) : "memory");
    } else if (kt + 64 < K) {
      asm volatile("s_waitcnt vmcnt(%0)" ::"n"(NLT) : "memory");
    } else {
      asm volatile("s_waitcnt vmcnt(0)" ::: "memory");
    }
    __builtin_amdgcn_s_barrier();       // (1) buf[cur] staged, all waves
    __builtin_amdgcn_sched_barrier(0);  // pin reads below the barrier

    short8 a[4][2], b[NJ][2];
    const unsigned short* Sc = &S[cur * BUFE];
#pragma unroll
    for (int i = 0; i < 4; ++i) {
      const int R = wmo + i * 16 + l15;
#pragma unroll
      for (int kh = 0; kh < 2; ++kh)
        a[i][kh] = *(const short8*)&Sc[R * 64 + (((kh * 4 + quad) ^ (R & 7)) * 8)];
    }
#pragma unroll
    for (int j = 0; j < NJ; ++j) {
      const int R = BM + wno + j * 16 + l15;
#pragma unroll
      for (int kh = 0; kh < 2; ++kh)
        b[j][kh] = *(const short8*)&Sc[R * 64 + (((kh * 4 + quad) ^ (R & 7)) * 8)];
    }
    asm volatile("s_waitcnt lgkmcnt(0)" ::: "memory");  // frags in regs
    __builtin_amdgcn_sched_barrier(0);
    __builtin_amdgcn_s_barrier();       // (2) all reads done -> buf reusable

    __builtin_amdgcn_s_setprio(1);
#pragma unroll
    for (int kh = 0; kh < 2; ++kh)
#pragma unroll
      for (int i = 0; i < 4; ++i)
#pragma unroll
        for (int j = 0; j < NJ; ++j)
          acc[i][j] = __builtin_amdgcn_mfma_f32_16x16x32_bf16(
              a[i][kh], b[j][kh], acc[i][j], 0, 0, 0);
    __builtin_amdgcn_s_setprio(0);

    ++cur;
    if (cur >= 3) cur -= 3;
  }

#pragma unroll
  for (int j = 0; j < NJ; ++j) {
    const int n = (int)n0 + wno + j * 16 + l15;
    const float bv = bias[n];
    const float sc = (EPI == 3 && n < 1024) ? 0.125f : 1.0f;
#pragma unroll
    for (int i = 0; i < 4; ++i) {
      const int mbase = (int)m0 + wmo + i * 16 + quad * 4;
#pragma unroll
      for (int r = 0; r < 4; ++r) {
        float v = acc[i][j][r] + bv;
        if (EPI == 2) v = 0.5f * v * (1.0f + erff(v * 0.70710678f));
        if (EPI == 3) v *= sc;
        size_t idx = (size_t)(mbase + r) * (size_t)N + n;
        if (EPI == 1) ((float*)outp)[idx] = v;
        else ((unsigned short*)outp)[idx] = f2bf(v);
      }
    }
  }
}

// ---------------------------------------------------------------------------
// Flash attention, sliding window (0 <= qpos-kpos <= 1000), 1 virtual past key
// (k=bk, v=bv). qkv: [B*T,3072] bf16 (0.125*q | k | v). Block = (qtile=128,
// head, batch), 8 waves x 16 queries.
// R5 = R3's PROVEN dataflow (Vt rotate-transpose, Ps, masks, denominators)
// + the two gemm3-verified upgrades (R4's tr_read V-path dropped - it was the
// unverifiable piece of the failed R4):
//  - Qs/Ks XOR chunk swizzle (G4/rule21): source chunk c^(row&7), linear LDS
//    dest, reads at (ks*4+quad)^(l15&7). Kills the 16-way ds_read_b128
//    conflict that dominated R3 (9.28M conflicts/dispatch).
//  - K AND V staged via async16 into double-buffered LDS (Vrow linear strip),
//    counted vmcnt(2) steady state - stage t+1 issued a full tile of compute
//    ahead; never drains mid-loop. All vmem = ordered intrinsics so the
//    manual count is deterministic (the R4 plain-load mixing hazard avoided).
//  - V transpose now LDS->LDS (Vrow -> Vt stride-72, R3's bank rotation),
//    inside the covered region. 2 raw barriers/iter: (1) post-vmcnt = staged
//    buffers visible; (2) post-lgkmcnt = Vt + all reads done. Virtual-key
//    overwrites are wave-0-ordered after the transpose, visible via (2).
// ---------------------------------------------------------------------------
__global__ __launch_bounds__(512) void attn_kernel(
    const unsigned short* __restrict__ qkv, const float* __restrict__ bqkv_l,
    unsigned short* __restrict__ attno) {
  __shared__ unsigned short Qs[128 * 64];      // [q][d] chunk-swizzled
  __shared__ unsigned short Ks[2][64 * 64];    // [k][d] chunk-swizzled
  __shared__ unsigned short Vrow[2][64 * 64];  // [k][d] linear async strip
  __shared__ unsigned short Vt[64 * 72];       // [d][k] stride 72
  __shared__ unsigned short Ps[8][16 * 72];    // per-wave P [q][k] stride 72
  __shared__ float Lsh[8][16];                 // per-wave softmax denominators

  const int qt = blockIdx.x, h = blockIdx.y, b = blockIdx.z;
  const int qs = qt * 128;
  const int tid = threadIdx.x, lane = tid & 63, wid = tid >> 6;
  const int quad = lane >> 4, l15 = lane & 15;
  const size_t rowbase = (size_t)b * 2048;
  const int hoff = h * 64;

#pragma unroll
  for (int r = 0; r < 2; ++r) {  // stage Q tile (16 KB), swizzled source
    int c = r * 512 + tid;
    int qrow = c >> 3, ccq = c & 7;
    async16(qkv + (rowbase + qs + qrow) * 3072 + hoff + ((ccq ^ (qrow & 7)) * 8),
            &Qs[c * 8]);
  }

  floatx4 oacc[4] = {};
  float lpart = 0.f;  // this lane's partial denominator for q = l15

  int kstart = qs - 999;
  if (kstart < 0) kstart = 0;
  kstart &= ~63;
  const int kend = qs + 128;

  const int krow = tid >> 3, cc = tid & 7;   // staging coords (512 thr = 64x8)
  const int qlo = qs + wid * 16 + 1;         // min qpos in this wave
  const int qhi = qlo + 15;                  // max qpos in this wave
  const int qpos = qs + wid * 16 + l15 + 1;  // this lane's qpos (S^T: q = l15)

  auto stageKV = [&](int buf, int k0) {
    int xr = k0 + krow - 1;
    xr = xr < 0 ? 0 : (xr > 2047 ? 2047 : xr);  // OOB rows masked later
    async16(qkv + (rowbase + xr) * 3072 + 1024 + hoff + ((cc ^ (krow & 7)) * 8),
            &Ks[buf][tid * 8]);
    async16(qkv + (rowbase + xr) * 3072 + 2048 + hoff + cc * 8,
            &Vrow[buf][tid * 8]);
  };

  stageKV(0, kstart);
  int cur = 0;

  for (int k0 = kstart; k0 <= kend; k0 += 64) {
    if (k0 + 64 <= kend) {
      stageKV(cur ^ 1, k0 + 64);
      asm volatile("s_waitcnt vmcnt(2)" ::: "memory");  // retire tile t (+Q)
    } else {
      asm volatile("s_waitcnt vmcnt(0)" ::: "memory");
    }
    __builtin_amdgcn_s_barrier();       // (1) Ks/Vrow[cur] staged, all waves
    __builtin_amdgcn_sched_barrier(0);

    if (k0 == 0) {  // virtual past key 0: k=bk (row 0 swizzle = identity)
      if (tid < 64) Ks[cur][tid] = f2bf(bqkv_l[1024 + hoff + tid]);
      __syncthreads();
    }

    {  // transpose Vrow[cur] -> Vt; rotate element order by cc (bank spread)
      short8 vv = *(const short8*)&Vrow[cur][tid * 8];
#pragma unroll
      for (int e = 0; e < 8; ++e) {
        int e2 = (e + cc) & 7;
        Vt[(cc * 8 + e2) * 72 + krow] = (unsigned short)vv[e2];
      }
      // virtual past key 0: v=bv. Same wave (0) as transpose writers of
      // Vt[d][0] -> same-wave LDS order makes this the final value.
      if (k0 == 0 && tid < 64) Vt[tid * 72] = f2bf(bqkv_l[2048 + hoff + tid]);
    }

    // wave-uniform: does this tile intersect this wave's window at all?
    const bool act = (k0 <= qhi) && (qlo - (k0 + 63) <= 1000);
    if (act) {
      // S^T = K*Q^T : D[key][q], key = nj*16+quad*4+r, q = l15
      floatx4 sacc[4] = {};
#pragma unroll
      for (int ks = 0; ks < 2; ++ks) {
        short8 bq = *(const short8*)&Qs[(wid * 16 + l15) * 64 +
                                        (((ks * 4 + quad) ^ (l15 & 7)) * 8)];
#pragma unroll
        for (int nj = 0; nj < 4; ++nj) {
          short8 ak = *(const short8*)&Ks[cur][(nj * 16 + l15) * 64 +
                                              (((ks * 4 + quad) ^ (l15 & 7)) * 8)];
          sacc[nj] = __builtin_amdgcn_mfma_f32_16x16x32_bf16(ak, bq, sacc[nj], 0, 0, 0);
        }
      }

      const bool full = (k0 + 63 <= qlo) && (qhi - k0 <= 1000);
#pragma unroll
      for (int nj = 0; nj < 4; ++nj) {
        float e[4];
        if (full) {
#pragma unroll
          for (int r = 0; r < 4; ++r) e[r] = __expf(sacc[nj][r]);
        } else {
          const int keyb = k0 + nj * 16 + quad * 4;
#pragma unroll
          for (int r = 0; r < 4; ++r) {
            int delta = qpos - (keyb + r);
            e[r] = (delta >= 0 && delta <= 1000) ? __expf(sacc[nj][r]) : 0.f;
          }
        }
        lpart += (e[0] + e[1]) + (e[2] + e[3]);
        uint2 pk = make_uint2(pack_bf2(e[0], e[1]), pack_bf2(e[2], e[3]));
        *(uint2*)&Ps[wid][l15 * 72 + nj * 16 + quad * 4] = pk;
      }
    }

    asm volatile("s_waitcnt lgkmcnt(0)" ::: "memory");  // Vt writes + reads done
    __builtin_amdgcn_sched_barrier(0);
    __builtin_amdgcn_s_barrier();       // (2) Vt (+virtual key) visible
    __builtin_amdgcn_sched_barrier(0);

    if (act) {
      // O += P V  (Ps wave-private; Vt visible after barrier (2))
#pragma unroll
      for (int ks = 0; ks < 2; ++ks) {
        short8 pf = *(const short8*)&Ps[wid][l15 * 72 + ks * 32 + quad * 8];
#pragma unroll
        for (int di = 0; di < 4; ++di) {
          short8 vf = *(const short8*)&Vt[(di * 16 + l15) * 72 + ks * 32 + quad * 8];
          oacc[di] = __builtin_amdgcn_mfma_f32_16x16x32_bf16(pf, vf, oacc[di], 0, 0, 0);
        }
      }
    }
    cur ^= 1;
  }

  // denominator: lpart is per (q=l15, quad) -> reduce over quads, redistribute
  lpart += __shfl_xor(lpart, 16);
  lpart += __shfl_xor(lpart, 32);
  if (quad == 0) Lsh[wid][l15] = lpart;
  __builtin_amdgcn_s_waitcnt(0);  // ds_write visible to own wave's reads
  float linv[4];
#pragma unroll
  for (int r = 0; r < 4; ++r) linv[r] = 1.0f / Lsh[wid][quad * 4 + r];

#pragma unroll
  for (int di = 0; di < 4; ++di)
#pragma unroll
    for (int r = 0; r < 4; ++r) {
      int q = qs + wid * 16 + quad * 4 + r;
      attno[(rowbase + q) * 1024 + hoff + di * 16 + l15] =
          f2bf(oacc[di][r] * linv[r]);
    }
}

// ---------------------------------------------------------------------------
// LN (+posemb) kernels: one block per row of 1024  (unchanged)
// ---------------------------------------------------------------------------
__global__ __launch_bounds__(256) void ln_first_kernel(
    const float* __restrict__ xin, const float* __restrict__ g,
    const float* __restrict__ bb, float* __restrict__ xout,
    unsigned short* __restrict__ xbout) {
  const int row = blockIdx.x, tid = threadIdx.x;
  const size_t base = (size_t)row * 1024 + tid * 4;
  float4 xv = *(const float4*)&xin[base];
  float s = xv.x + xv.y + xv.z + xv.w;
  float sq = xv.x * xv.x + xv.y * xv.y + xv.z * xv.z + xv.w * xv.w;
  __shared__ float red[8];
  for (int off = 32; off > 0; off >>= 1) { s += __shfl_down(s, off); sq += __shfl_down(sq, off); }
  if ((tid & 63) == 0) { red[tid >> 6] = s; red[4 + (tid >> 6)] = sq; }
  __syncthreads();
  s = red[0] + red[1] + red[2] + red[3];
  sq = red[4] + red[5] + red[6] + red[7];
  const float mean = s * (1.f / 1024.f);
  const float rstd = rsqrtf(sq * (1.f / 1024.f) - mean * mean + 1e-5f);
  float4 gv = *(const float4*)&g[tid * 4];
  float4 bv = *(const float4*)&bb[tid * 4];
  const float tf = (float)(row & 2047);
  float xs[4] = {xv.x, xv.y, xv.z, xv.w};
  float gs[4] = {gv.x, gv.y, gv.z, gv.w};
  float bs[4] = {bv.x, bv.y, bv.z, bv.w};
  float y[4];
#pragma unroll
  for (int e = 0; e < 4; ++e) {
    int c = tid * 4 + e;
    float a = (c < 512) ? (float)c : (float)(c - 512);
    float ph = tf * powf(10000.f, -a * (1.f / 511.f));
    float pe = (c < 512) ? cosf(ph) : sinf(ph);
    y[e] = (xs[e] - mean) * rstd * gs[e] + bs[e] + pe;
  }
  *(float4*)&xout[base] = make_float4(y[0], y[1], y[2], y[3]);
  *(ushort4*)&xbout[base] = make_ushort4(f2bf(y[0]), f2bf(y[1]), f2bf(y[2]), f2bf(y[3]));
}

__global__ __launch_bounds__(256) void ln_res_kernel(
    const float* __restrict__ xin, const float* __restrict__ addv,
    const float* __restrict__ g, const float* __restrict__ bb,
    float* __restrict__ xout, unsigned short* __restrict__ xbout) {
  const int row = blockIdx.x, tid = threadIdx.x;
  const size_t base = (size_t)row * 1024 + tid * 4;
  float4 xv = *(const float4*)&xin[base];
  float4 av = *(const float4*)&addv[base];
  float v0 = xv.x + av.x, v1 = xv.y + av.y, v2 = xv.z + av.z, v3 = xv.w + av.w;
  float s = v0 + v1 + v2 + v3;
  float sq = v0 * v0 + v1 * v1 + v2 * v2 + v3 * v3;
  __shared__ float red[8];
  for (int off = 32; off > 0; off >>= 1) { s += __shfl_down(s, off); sq += __shfl_down(sq, off); }
  if ((tid & 63) == 0) { red[tid >> 6] = s; red[4 + (tid >> 6)] = sq; }
  __syncthreads();
  s = red[0] + red[1] + red[2] + red[3];
  sq = red[4] + red[5] + red[6] + red[7];
  const float mean = s * (1.f / 1024.f);
  const float rstd = rsqrtf(sq * (1.f / 1024.f) - mean * mean + 1e-5f);
  float4 gv = *(const float4*)&g[tid * 4];
  float4 bv = *(const float4*)&bb[tid * 4];
  float vs[4] = {v0, v1, v2, v3};
  float gs[4] = {gv.x, gv.y, gv.z, gv.w};
  float bs[4] = {bv.x, bv.y, bv.z, bv.w};
  float y[4];
#pragma unroll
  for (int e = 0; e < 4; ++e) y[e] = (vs[e] - mean) * rstd * gs[e] + bs[e];
  *(float4*)&xout[base] = make_float4(y[0], y[1], y[2], y[3]);
  if (xbout)
    *(ushort4*)&xbout[base] = make_ushort4(f2bf(y[0]), f2bf(y[1]), f2bf(y[2]), f2bf(y[3]));
}

// fp32 -> bf16 weight conversion for one layer (Wqkv|Wo|W1|W2 concat)
__global__ __launch_bounds__(256) void convw_kernel(
    const float* __restrict__ wqkv, const float* __restrict__ wo,
    const float* __restrict__ w1, const float* __restrict__ w2,
    unsigned short* __restrict__ dst) {
  for (int base = blockIdx.x * 256 + threadIdx.x; base < 3145728; base += 786432) {
    int i = base << 2;
    const float* src;
    int off;
    if (i < 3145728)      { src = wqkv; off = i; }
    else if (i < 4194304) { src = wo;   off = i - 3145728; }
    else if (i < 8388608) { src = w1;   off = i - 4194304; }
    else                  { src = w2;   off = i - 8388608; }
    float4 v = *(const float4*)&src[off];
    *(ushort4*)&dst[i] = make_ushort4(f2bf(v.x), f2bf(v.y), f2bf(v.z), f2bf(v.w));
  }
}

// ---------------------------------------------------------------------------
extern "C" void kernel_launch(void* const* d_in, const int* in_sizes, int n_in,
                              void* d_out, int out_size, void* d_ws, size_t ws_size,
                              hipStream_t stream) {
  const float* x    = (const float*)d_in[0];
  const float* ng   = (const float*)d_in[1];
  const float* nb   = (const float*)d_in[2];
  const float* Wqkv = (const float*)d_in[3];
  const float* bqkv = (const float*)d_in[4];
  const float* Wo   = (const float*)d_in[5];
  const float* bo   = (const float*)d_in[6];
  const float* ln1g = (const float*)d_in[7];
  const float* ln1b = (const float*)d_in[8];
  const float* ln2g = (const float*)d_in[9];
  const float* ln2b = (const float*)d_in[10];
  const float* W1   = (const float*)d_in[11];
  const float* b1   = (const float*)d_in[12];
  const float* W2   = (const float*)d_in[13];
  const float* b2   = (const float*)d_in[14];

  char* ws = (char*)d_ws;  // total footprint: exactly 128 MiB
  float* xf           = (float*)(ws + 0);          // 16 MB fp32 residual stream
  unsigned short* xb  = (unsigned short*)(ws + 16777216);   // 8 MB bf16 copy
  unsigned short* qkv = (unsigned short*)(ws + 25165824);   // 24 MB bf16 [4096,3072]
  unsigned short* att = (unsigned short*)(ws + 50331648);   // 8 MB bf16
  unsigned short* h1  = (unsigned short*)(ws + 58720256);   // 32 MB bf16 [4096,4096]
  float* gout         = (float*)(ws + 92274688);            // 16 MB fp32 GEMM out
  unsigned short* wb  = (unsigned short*)(ws + 109051904);  // 24 MB bf16 weights
  unsigned short* wqkvb = wb;
  unsigned short* wob   = wb + 3145728;
  unsigned short* w1b   = wb + 4194304;
  unsigned short* w2b   = wb + 8388608;

  ln_first_kernel<<<4096, 256, 0, stream>>>(x, ng, nb, xf, xb);

  for (int l = 0; l < 6; ++l) {
    convw_kernel<<<3072, 256, 0, stream>>>(Wqkv + (size_t)l * 3145728,
                                           Wo + (size_t)l * 1048576,
                                           W1 + (size_t)l * 4194304,
                                           W2 + (size_t)l * 4194304, wb);
    gemm3<3, 256><<<dim3(24, 16), 512, 0, stream>>>(xb, wqkvb, bqkv + l * 3072, qkv,
                                                    4096, 3072, 1024);
    attn_kernel<<<dim3(16, 16, 2), 512, 0, stream>>>(qkv, bqkv + l * 3072, att);
    gemm3<1, 128><<<dim3(8, 32), 512, 0, stream>>>(att, wob, bo + l * 1024, gout,
                                                   4096, 1024, 1024);
    ln_res_kernel<<<4096, 256, 0, stream>>>(xf, gout, ln1g + l * 1024, ln1b + l * 1024,
                                            xf, xb);
    gemm3<2, 256><<<dim3(32, 16), 512, 0, stream>>>(xb, w1b, b1 + l * 4096, h1,
                                                    4096, 4096, 1024);
    gemm3<1, 64 + 64><<<dim3(8, 32), 512, 0, stream>>>(h1, w2b, b2 + l * 1024, gout,
                                                       4096, 1024, 4096);
    // Final output is fp32: last LN writes directly to d_out as float.
    ln_res_kernel<<<4096, 256, 0, stream>>>(xf, gout, ln2g + l * 1024, ln2b + l * 1024,
                                            (l == 5) ? (float*)d_out : xf,
                                            (l == 5) ? nullptr : xb);
  }
}

// Round 6
// 1687.578 us; speedup vs baseline: 1.1613x; 1.0304x over previous
//
#include <hip/hip_runtime.h>
#include <math.h>

typedef short short8 __attribute__((ext_vector_type(8)));
typedef float floatx4 __attribute__((ext_vector_type(4)));

__device__ __forceinline__ unsigned short f2bf(float f) {
  unsigned int u = __builtin_bit_cast(unsigned int, f);
  u = (u + 0x7FFFu + ((u >> 16) & 1u)) >> 16;
  return (unsigned short)u;
}

__device__ __forceinline__ unsigned int pack_bf2(float lo, float hi) {
  return (unsigned int)f2bf(lo) | ((unsigned int)f2bf(hi) << 16);
}

__device__ __forceinline__ void async16(const void* g, void* l) {
  __builtin_amdgcn_global_load_lds(
      (const __attribute__((address_space(1))) unsigned int*)g,
      (__attribute__((address_space(3))) unsigned int*)l, 16, 0, 0);
}

// ---------------------------------------------------------------------------
// GEMM R6: out[M,N] = A[M,K]*B[N,K]^T + bias[N]   (A,B bf16 K-major)
// EPI: 1 = fp32 out, 2 = bf16 + exact GELU, 3 = bf16, n<1024 scaled 0.125
// BM: 256 (waves 4Mx2N... NJ=4) or 128 (2Mx4N, NJ=2). BN=128. BK=64.
//
// R5 post-mortem: MfmaUtil 20.6% == exact MFMA-busy/dur ratio; VALUBusy 36.6%.
// Two baked-in costs: (a) lgkmcnt(0)+barrier BETWEEN read phase and MFMA phase
// lockstepped all 8 waves -> MFMA pipe idle during every read drain;
// (b) staging/read addresses fully recomputed per iter (~1750 VALU cyc/iter).
// R6:
//  - ONE barrier per iter (trailing). Safe with the triple ring: each wave's
//    frag reads are consumed by its MFMAs before the barrier (compiler data
//    deps force lgkm drain), and the overwriting stage for a slot is issued
//    only after the next barrier. vmcnt(NLT) counted before the barrier
//    (never 0 mid-loop); sched_barrier(0) after it pins next iter's reads
//    and stages below.
//  - Incremental addressing: 6 stage pointers advance +64 elem/iter; all 24
//    read offsets loop-invariant in registers.
//  - XOR chunk swizzle + XCD-bijective block swizzle + setprio unchanged.
// ---------------------------------------------------------------------------
template <int EPI, int BM>
__global__ __launch_bounds__(512, 2) void gemm3(
    const unsigned short* __restrict__ A, const unsigned short* __restrict__ B,
    const float* __restrict__ bias, void* __restrict__ outp,
    int M, int N, int K) {
  constexpr int BN = 128;
  constexpr int ROWS = BM + BN;           // A rows then B rows per buffer
  constexpr int BUFE = ROWS * 64;         // elems per buffer
  constexpr int NLT = ROWS / 64;          // gloads/thread/tile (6 or 4)
  constexpr int WM = BM / 64;             // waves along M (4 or 2)
  constexpr int WN = 8 / WM;              // waves along N (2 or 4)
  constexpr int NJ = (BN / WN) / 16;      // 4 or 2 j-fragments
  __shared__ unsigned short S[3 * BUFE];  // 144 KB (BM=256) / 96 KB (BM=128)

  const int tid = threadIdx.x;
  const int lane = tid & 63, wid = tid >> 6;
  const int quad = lane >> 4, l15 = lane & 15;
  const int wm = wid / WN, wn = wid % WN;
  const int wmo = wm * 64;
  const int wno = wn * (BN / WN);

  // XCD-aware bijective swizzle (nwg % 8 == 0 for all launches)
  const int gx = gridDim.x;
  const int nwg = gx * gridDim.y;
  int lin = blockIdx.y * gx + blockIdx.x;
  lin = (lin & 7) * (nwg >> 3) + (lin >> 3);
  const size_t m0 = (size_t)(lin / gx) * BM;
  const size_t n0 = (size_t)(lin % gx) * BN;

  // per-thread staging sources (advance +64 elems per staged K-tile)
  const unsigned short* sp[NLT];
  unsigned ldst[NLT];
#pragma unroll
  for (int l = 0; l < NLT; ++l) {
    int ci = l * 512 + tid;
    int r = ci >> 3;
    int c = (ci & 7) ^ (r & 7);  // pre-swizzled logical chunk
    sp[l] = (r < BM ? A + (m0 + r) * (size_t)K
                    : B + (n0 + (r - BM)) * (size_t)K) + c * 8;
    ldst[l] = (unsigned)ci * 8;
  }
  auto stage = [&](int buf) {
#pragma unroll
    for (int l = 0; l < NLT; ++l) {
      async16(sp[l], &S[buf * BUFE + ldst[l]]);
      sp[l] += 64;
    }
  };

  // loop-invariant fragment read offsets (element units)
  int aoff[4][2], boff[NJ][2];
#pragma unroll
  for (int i = 0; i < 4; ++i) {
    const int R = wmo + i * 16 + l15;
#pragma unroll
    for (int kh = 0; kh < 2; ++kh)
      aoff[i][kh] = R * 64 + (((kh * 4 + quad) ^ (R & 7)) * 8);
  }
#pragma unroll
  for (int j = 0; j < NJ; ++j) {
    const int R = BM + wno + j * 16 + l15;
#pragma unroll
    for (int kh = 0; kh < 2; ++kh)
      boff[j][kh] = R * 64 + (((kh * 4 + quad) ^ (R & 7)) * 8);
  }

  floatx4 acc[4][NJ] = {};

  stage(0);
  stage(1);
  asm volatile("s_waitcnt vmcnt(%0)" ::"n"(NLT) : "memory");
  __builtin_amdgcn_s_barrier();
  __builtin_amdgcn_sched_barrier(0);
  int cur = 0;

  for (int kt = 0; kt < K; kt += 64) {
    const unsigned short* Sc = &S[cur * BUFE];
    short8 a[4][2], b[NJ][2];
#pragma unroll
    for (int i = 0; i < 4; ++i)
#pragma unroll
      for (int kh = 0; kh < 2; ++kh)
        a[i][kh] = *(const short8*)&Sc[aoff[i][kh]];
#pragma unroll
    for (int j = 0; j < NJ; ++j)
#pragma unroll
      for (int kh = 0; kh < 2; ++kh)
        b[j][kh] = *(const short8*)&Sc[boff[j][kh]];

    if (kt + 128 < K) {
      int nb = cur + 2;
      if (nb >= 3) nb -= 3;
      stage(nb);
    }

    __builtin_amdgcn_s_setprio(1);
#pragma unroll
    for (int kh = 0; kh < 2; ++kh)
#pragma unroll
      for (int i = 0; i < 4; ++i)
#pragma unroll
        for (int j = 0; j < NJ; ++j)
          acc[i][j] = __builtin_amdgcn_mfma_f32_16x16x32_bf16(
              a[i][kh], b[j][kh], acc[i][j], 0, 0, 0);
    __builtin_amdgcn_s_setprio(0);

    // trailing sync: next buffer landed (counted, never 0 mid-loop); all
    // waves' reads of this slot are in regs (consumed by MFMAs above).
    if (kt + 128 < K) {
      asm volatile("s_waitcnt vmcnt(%0)" ::"n"(NLT) : "memory");
    } else if (kt + 64 < K) {
      asm volatile("s_waitcnt vmcnt(0)" ::: "memory");
    }
    __builtin_amdgcn_s_barrier();
    __builtin_amdgcn_sched_barrier(0);  // pin next reads/stages below

    ++cur;
    if (cur >= 3) cur -= 3;
  }

#pragma unroll
  for (int j = 0; j < NJ; ++j) {
    const int n = (int)n0 + wno + j * 16 + l15;
    const float bv = bias[n];
    const float sc = (EPI == 3 && n < 1024) ? 0.125f : 1.0f;
#pragma unroll
    for (int i = 0; i < 4; ++i) {
      const int mbase = (int)m0 + wmo + i * 16 + quad * 4;
#pragma unroll
      for (int r = 0; r < 4; ++r) {
        float v = acc[i][j][r] + bv;
        if (EPI == 2) v = 0.5f * v * (1.0f + erff(v * 0.70710678f));
        if (EPI == 3) v *= sc;
        size_t idx = (size_t)(mbase + r) * (size_t)N + n;
        if (EPI == 1) ((float*)outp)[idx] = v;
        else ((unsigned short*)outp)[idx] = f2bf(v);
      }
    }
  }
}

// ---------------------------------------------------------------------------
// Flash attention (R5, verified): sliding window, 1 virtual past key.
// Qs/Ks XOR chunk swizzle; K/V async16 double-buffer, counted vmcnt(2);
// LDS->LDS V transpose (rotate); 2 raw barriers/iter.
// ---------------------------------------------------------------------------
__global__ __launch_bounds__(512) void attn_kernel(
    const unsigned short* __restrict__ qkv, const float* __restrict__ bqkv_l,
    unsigned short* __restrict__ attno) {
  __shared__ unsigned short Qs[128 * 64];      // [q][d] chunk-swizzled
  __shared__ unsigned short Ks[2][64 * 64];    // [k][d] chunk-swizzled
  __shared__ unsigned short Vrow[2][64 * 64];  // [k][d] linear async strip
  __shared__ unsigned short Vt[64 * 72];       // [d][k] stride 72
  __shared__ unsigned short Ps[8][16 * 72];    // per-wave P [q][k] stride 72
  __shared__ float Lsh[8][16];                 // per-wave softmax denominators

  const int qt = blockIdx.x, h = blockIdx.y, b = blockIdx.z;
  const int qs = qt * 128;
  const int tid = threadIdx.x, lane = tid & 63, wid = tid >> 6;
  const int quad = lane >> 4, l15 = lane & 15;
  const size_t rowbase = (size_t)b * 2048;
  const int hoff = h * 64;

#pragma unroll
  for (int r = 0; r < 2; ++r) {  // stage Q tile (16 KB), swizzled source
    int c = r * 512 + tid;
    int qrow = c >> 3, ccq = c & 7;
    async16(qkv + (rowbase + qs + qrow) * 3072 + hoff + ((ccq ^ (qrow & 7)) * 8),
            &Qs[c * 8]);
  }

  floatx4 oacc[4] = {};
  float lpart = 0.f;  // this lane's partial denominator for q = l15

  int kstart = qs - 999;
  if (kstart < 0) kstart = 0;
  kstart &= ~63;
  const int kend = qs + 128;

  const int krow = tid >> 3, cc = tid & 7;   // staging coords (512 thr = 64x8)
  const int qlo = qs + wid * 16 + 1;         // min qpos in this wave
  const int qhi = qlo + 15;                  // max qpos in this wave
  const int qpos = qs + wid * 16 + l15 + 1;  // this lane's qpos (S^T: q = l15)

  auto stageKV = [&](int buf, int k0) {
    int xr = k0 + krow - 1;
    xr = xr < 0 ? 0 : (xr > 2047 ? 2047 : xr);  // OOB rows masked later
    async16(qkv + (rowbase + xr) * 3072 + 1024 + hoff + ((cc ^ (krow & 7)) * 8),
            &Ks[buf][tid * 8]);
    async16(qkv + (rowbase + xr) * 3072 + 2048 + hoff + cc * 8,
            &Vrow[buf][tid * 8]);
  };

  stageKV(0, kstart);
  int cur = 0;

  for (int k0 = kstart; k0 <= kend; k0 += 64) {
    if (k0 + 64 <= kend) {
      stageKV(cur ^ 1, k0 + 64);
      asm volatile("s_waitcnt vmcnt(2)" ::: "memory");  // retire tile t (+Q)
    } else {
      asm volatile("s_waitcnt vmcnt(0)" ::: "memory");
    }
    __builtin_amdgcn_s_barrier();       // (1) Ks/Vrow[cur] staged, all waves
    __builtin_amdgcn_sched_barrier(0);

    if (k0 == 0) {  // virtual past key 0: k=bk (row 0 swizzle = identity)
      if (tid < 64) Ks[cur][tid] = f2bf(bqkv_l[1024 + hoff + tid]);
      __syncthreads();
    }

    {  // transpose Vrow[cur] -> Vt; rotate element order by cc (bank spread)
      short8 vv = *(const short8*)&Vrow[cur][tid * 8];
#pragma unroll
      for (int e = 0; e < 8; ++e) {
        int e2 = (e + cc) & 7;
        Vt[(cc * 8 + e2) * 72 + krow] = (unsigned short)vv[e2];
      }
      // virtual past key 0: v=bv (same wave 0 as Vt[d][0] writers -> ordered)
      if (k0 == 0 && tid < 64) Vt[tid * 72] = f2bf(bqkv_l[2048 + hoff + tid]);
    }

    // wave-uniform: does this tile intersect this wave's window at all?
    const bool act = (k0 <= qhi) && (qlo - (k0 + 63) <= 1000);
    if (act) {
      // S^T = K*Q^T : D[key][q], key = nj*16+quad*4+r, q = l15
      floatx4 sacc[4] = {};
#pragma unroll
      for (int ks = 0; ks < 2; ++ks) {
        short8 bq = *(const short8*)&Qs[(wid * 16 + l15) * 64 +
                                        (((ks * 4 + quad) ^ (l15 & 7)) * 8)];
#pragma unroll
        for (int nj = 0; nj < 4; ++nj) {
          short8 ak = *(const short8*)&Ks[cur][(nj * 16 + l15) * 64 +
                                              (((ks * 4 + quad) ^ (l15 & 7)) * 8)];
          sacc[nj] = __builtin_amdgcn_mfma_f32_16x16x32_bf16(ak, bq, sacc[nj], 0, 0, 0);
        }
      }

      const bool full = (k0 + 63 <= qlo) && (qhi - k0 <= 1000);
#pragma unroll
      for (int nj = 0; nj < 4; ++nj) {
        float e[4];
        if (full) {
#pragma unroll
          for (int r = 0; r < 4; ++r) e[r] = __expf(sacc[nj][r]);
        } else {
          const int keyb = k0 + nj * 16 + quad * 4;
#pragma unroll
          for (int r = 0; r < 4; ++r) {
            int delta = qpos - (keyb + r);
            e[r] = (delta >= 0 && delta <= 1000) ? __expf(sacc[nj][r]) : 0.f;
          }
        }
        lpart += (e[0] + e[1]) + (e[2] + e[3]);
        uint2 pk = make_uint2(pack_bf2(e[0], e[1]), pack_bf2(e[2], e[3]));
        *(uint2*)&Ps[wid][l15 * 72 + nj * 16 + quad * 4] = pk;
      }
    }

    asm volatile("s_waitcnt lgkmcnt(0)" ::: "memory");  // Vt writes + reads done
    __builtin_amdgcn_sched_barrier(0);
    __builtin_amdgcn_s_barrier();       // (2) Vt (+virtual key) visible
    __builtin_amdgcn_sched_barrier(0);

    if (act) {
      // O += P V  (Ps wave-private; Vt visible after barrier (2))
#pragma unroll
      for (int ks = 0; ks < 2; ++ks) {
        short8 pf = *(const short8*)&Ps[wid][l15 * 72 + ks * 32 + quad * 8];
#pragma unroll
        for (int di = 0; di < 4; ++di) {
          short8 vf = *(const short8*)&Vt[(di * 16 + l15) * 72 + ks * 32 + quad * 8];
          oacc[di] = __builtin_amdgcn_mfma_f32_16x16x32_bf16(pf, vf, oacc[di], 0, 0, 0);
        }
      }
    }
    cur ^= 1;
  }

  // denominator: lpart is per (q=l15, quad) -> reduce over quads, redistribute
  lpart += __shfl_xor(lpart, 16);
  lpart += __shfl_xor(lpart, 32);
  if (quad == 0) Lsh[wid][l15] = lpart;
  __builtin_amdgcn_s_waitcnt(0);  // ds_write visible to own wave's reads
  float linv[4];
#pragma unroll
  for (int r = 0; r < 4; ++r) linv[r] = 1.0f / Lsh[wid][quad * 4 + r];

#pragma unroll
  for (int di = 0; di < 4; ++di)
#pragma unroll
    for (int r = 0; r < 4; ++r) {
      int q = qs + wid * 16 + quad * 4 + r;
      attno[(rowbase + q) * 1024 + hoff + di * 16 + l15] =
          f2bf(oacc[di][r] * linv[r]);
    }
}

// ---------------------------------------------------------------------------
// LN (+posemb) kernels: one block per row of 1024  (unchanged)
// ---------------------------------------------------------------------------
__global__ __launch_bounds__(256) void ln_first_kernel(
    const float* __restrict__ xin, const float* __restrict__ g,
    const float* __restrict__ bb, float* __restrict__ xout,
    unsigned short* __restrict__ xbout) {
  const int row = blockIdx.x, tid = threadIdx.x;
  const size_t base = (size_t)row * 1024 + tid * 4;
  float4 xv = *(const float4*)&xin[base];
  float s = xv.x + xv.y + xv.z + xv.w;
  float sq = xv.x * xv.x + xv.y * xv.y + xv.z * xv.z + xv.w * xv.w;
  __shared__ float red[8];
  for (int off = 32; off > 0; off >>= 1) { s += __shfl_down(s, off); sq += __shfl_down(sq, off); }
  if ((tid & 63) == 0) { red[tid >> 6] = s; red[4 + (tid >> 6)] = sq; }
  __syncthreads();
  s = red[0] + red[1] + red[2] + red[3];
  sq = red[4] + red[5] + red[6] + red[7];
  const float mean = s * (1.f / 1024.f);
  const float rstd = rsqrtf(sq * (1.f / 1024.f) - mean * mean + 1e-5f);
  float4 gv = *(const float4*)&g[tid * 4];
  float4 bv = *(const float4*)&bb[tid * 4];
  const float tf = (float)(row & 2047);
  float xs[4] = {xv.x, xv.y, xv.z, xv.w};
  float gs[4] = {gv.x, gv.y, gv.z, gv.w};
  float bs[4] = {bv.x, bv.y, bv.z, bv.w};
  float y[4];
#pragma unroll
  for (int e = 0; e < 4; ++e) {
    int c = tid * 4 + e;
    float a = (c < 512) ? (float)c : (float)(c - 512);
    float ph = tf * powf(10000.f, -a * (1.f / 511.f));
    float pe = (c < 512) ? cosf(ph) : sinf(ph);
    y[e] = (xs[e] - mean) * rstd * gs[e] + bs[e] + pe;
  }
  *(float4*)&xout[base] = make_float4(y[0], y[1], y[2], y[3]);
  *(ushort4*)&xbout[base] = make_ushort4(f2bf(y[0]), f2bf(y[1]), f2bf(y[2]), f2bf(y[3]));
}

__global__ __launch_bounds__(256) void ln_res_kernel(
    const float* __restrict__ xin, const float* __restrict__ addv,
    const float* __restrict__ g, const float* __restrict__ bb,
    float* __restrict__ xout, unsigned short* __restrict__ xbout) {
  const int row = blockIdx.x, tid = threadIdx.x;
  const size_t base = (size_t)row * 1024 + tid * 4;
  float4 xv = *(const float4*)&xin[base];
  float4 av = *(const float4*)&addv[base];
  float v0 = xv.x + av.x, v1 = xv.y + av.y, v2 = xv.z + av.z, v3 = xv.w + av.w;
  float s = v0 + v1 + v2 + v3;
  float sq = v0 * v0 + v1 * v1 + v2 * v2 + v3 * v3;
  __shared__ float red[8];
  for (int off = 32; off > 0; off >>= 1) { s += __shfl_down(s, off); sq += __shfl_down(sq, off); }
  if ((tid & 63) == 0) { red[tid >> 6] = s; red[4 + (tid >> 6)] = sq; }
  __syncthreads();
  s = red[0] + red[1] + red[2] + red[3];
  sq = red[4] + red[5] + red[6] + red[7];
  const float mean = s * (1.f / 1024.f);
  const float rstd = rsqrtf(sq * (1.f / 1024.f) - mean * mean + 1e-5f);
  float4 gv = *(const float4*)&g[tid * 4];
  float4 bv = *(const float4*)&bb[tid * 4];
  float vs[4] = {v0, v1, v2, v3};
  float gs[4] = {gv.x, gv.y, gv.z, gv.w};
  float bs[4] = {bv.x, bv.y, bv.z, bv.w};
  float y[4];
#pragma unroll
  for (int e = 0; e < 4; ++e) y[e] = (vs[e] - mean) * rstd * gs[e] + bs[e];
  *(float4*)&xout[base] = make_float4(y[0], y[1], y[2], y[3]);
  if (xbout)
    *(ushort4*)&xbout[base] = make_ushort4(f2bf(y[0]), f2bf(y[1]), f2bf(y[2]), f2bf(y[3]));
}

// fp32 -> bf16 weight conversion for one layer (Wqkv|Wo|W1|W2 concat)
__global__ __launch_bounds__(256) void convw_kernel(
    const float* __restrict__ wqkv, const float* __restrict__ wo,
    const float* __restrict__ w1, const float* __restrict__ w2,
    unsigned short* __restrict__ dst) {
  for (int base = blockIdx.x * 256 + threadIdx.x; base < 3145728; base += 786432) {
    int i = base << 2;
    const float* src;
    int off;
    if (i < 3145728)      { src = wqkv; off = i; }
    else if (i < 4194304) { src = wo;   off = i - 3145728; }
    else if (i < 8388608) { src = w1;   off = i - 4194304; }
    else                  { src = w2;   off = i - 8388608; }
    float4 v = *(const float4*)&src[off];
    *(ushort4*)&dst[i] = make_ushort4(f2bf(v.x), f2bf(v.y), f2bf(v.z), f2bf(v.w));
  }
}

// ---------------------------------------------------------------------------
extern "C" void kernel_launch(void* const* d_in, const int* in_sizes, int n_in,
                              void* d_out, int out_size, void* d_ws, size_t ws_size,
                              hipStream_t stream) {
  const float* x    = (const float*)d_in[0];
  const float* ng   = (const float*)d_in[1];
  const float* nb   = (const float*)d_in[2];
  const float* Wqkv = (const float*)d_in[3];
  const float* bqkv = (const float*)d_in[4];
  const float* Wo   = (const float*)d_in[5];
  const float* bo   = (const float*)d_in[6];
  const float* ln1g = (const float*)d_in[7];
  const float* ln1b = (const float*)d_in[8];
  const float* ln2g = (const float*)d_in[9];
  const float* ln2b = (const float*)d_in[10];
  const float* W1   = (const float*)d_in[11];
  const float* b1   = (const float*)d_in[12];
  const float* W2   = (const float*)d_in[13];
  const float* b2   = (const float*)d_in[14];

  char* ws = (char*)d_ws;  // total footprint: exactly 128 MiB
  float* xf           = (float*)(ws + 0);          // 16 MB fp32 residual stream
  unsigned short* xb  = (unsigned short*)(ws + 16777216);   // 8 MB bf16 copy
  unsigned short* qkv = (unsigned short*)(ws + 25165824);   // 24 MB bf16 [4096,3072]
  unsigned short* att = (unsigned short*)(ws + 50331648);   // 8 MB bf16
  unsigned short* h1  = (unsigned short*)(ws + 58720256);   // 32 MB bf16 [4096,4096]
  float* gout         = (float*)(ws + 92274688);            // 16 MB fp32 GEMM out
  unsigned short* wb  = (unsigned short*)(ws + 109051904);  // 24 MB bf16 weights
  unsigned short* wqkvb = wb;
  unsigned short* wob   = wb + 3145728;
  unsigned short* w1b   = wb + 4194304;
  unsigned short* w2b   = wb + 8388608;

  ln_first_kernel<<<4096, 256, 0, stream>>>(x, ng, nb, xf, xb);

  for (int l = 0; l < 6; ++l) {
    convw_kernel<<<3072, 256, 0, stream>>>(Wqkv + (size_t)l * 3145728,
                                           Wo + (size_t)l * 1048576,
                                           W1 + (size_t)l * 4194304,
                                           W2 + (size_t)l * 4194304, wb);
    gemm3<3, 256><<<dim3(24, 16), 512, 0, stream>>>(xb, wqkvb, bqkv + l * 3072, qkv,
                                                    4096, 3072, 1024);
    attn_kernel<<<dim3(16, 16, 2), 512, 0, stream>>>(qkv, bqkv + l * 3072, att);
    gemm3<1, 128><<<dim3(8, 32), 512, 0, stream>>>(att, wob, bo + l * 1024, gout,
                                                   4096, 1024, 1024);
    ln_res_kernel<<<4096, 256, 0, stream>>>(xf, gout, ln1g + l * 1024, ln1b + l * 1024,
                                            xf, xb);
    gemm3<2, 256><<<dim3(32, 16), 512, 0, stream>>>(xb, w1b, b1 + l * 4096, h1,
                                                    4096, 4096, 1024);
    gemm3<1, 128><<<dim3(8, 32), 512, 0, stream>>>(h1, w2b, b2 + l * 1024, gout,
                                                   4096, 1024, 4096);
    // Final output is fp32: last LN writes directly to d_out as float.
    ln_res_kernel<<<4096, 256, 0, stream>>>(xf, gout, ln2g + l * 1024, ln2b + l * 1024,
                                            (l == 5) ? (float*)d_out : xf,
                                            (l == 5) ? nullptr : xb);
  }
}